// Round 1
// baseline (249.967 us; speedup 1.0000x reference)
//
#include <hip/hip_runtime.h>

typedef __attribute__((ext_vector_type(8))) short short8;   // 8 bf16 = 4 VGPRs (MFMA A/B frag)
typedef __attribute__((ext_vector_type(4))) float f32x4;    // MFMA C/D frag

#define DIM 256
#define D4  64    // float4 per row
#define DCH 32    // 16B chunks (8 bf16) per row

// round-to-nearest-even fp32 -> bf16 (values are finite, no NaN handling needed)
__device__ __forceinline__ unsigned short f2bf(float f) {
  unsigned int u = __float_as_uint(f);
  u += 0x7fffu + ((u >> 16) & 1u);
  return (unsigned short)(u >> 16);
}

// One wave per row. Rows [0,N): pos pair -> pos_sim contribution + normalized pk (bf16).
// Rows [N,N+M): neg rows -> normalized nv (bf16).
__global__ __launch_bounds__(256) void normalize_kernel(
    const float4* __restrict__ pk, const float4* __restrict__ pv,
    const float4* __restrict__ nv, ushort4* __restrict__ pkn,
    ushort4* __restrict__ nvn, float* __restrict__ out,
    int N, float posScale) {
  int row  = blockIdx.x * 4 + (threadIdx.x >> 6);
  int lane = threadIdx.x & 63;
  if (row < N) {
    float4 x = pk[row * D4 + lane];
    float4 y = pv[row * D4 + lane];
    float skk = x.x*x.x + x.y*x.y + x.z*x.z + x.w*x.w;
    float svv = y.x*y.x + y.y*y.y + y.z*y.z + y.w*y.w;
    float skv = x.x*y.x + x.y*y.y + x.z*y.z + x.w*y.w;
#pragma unroll
    for (int m = 32; m >= 1; m >>= 1) {
      skk += __shfl_xor(skk, m, 64);
      svv += __shfl_xor(svv, m, 64);
      skv += __shfl_xor(skv, m, 64);
    }
    float nk  = fmaxf(sqrtf(skk), 1e-8f);
    float nvv = fmaxf(sqrtf(svv), 1e-8f);
    if (lane == 0) atomicAdd(out, -skv / (nk * nvv) * posScale);
    float rk = 1.0f / nk;
    ushort4 o;
    o.x = f2bf(x.x * rk); o.y = f2bf(x.y * rk);
    o.z = f2bf(x.z * rk); o.w = f2bf(x.w * rk);
    pkn[row * D4 + lane] = o;
  } else {
    int r2 = row - N;
    float4 x = nv[r2 * D4 + lane];
    float s = x.x*x.x + x.y*x.y + x.z*x.z + x.w*x.w;
#pragma unroll
    for (int m = 32; m >= 1; m >>= 1) s += __shfl_xor(s, m, 64);
    float rn = 1.0f / fmaxf(sqrtf(s), 1e-8f);
    ushort4 o;
    o.x = f2bf(x.x * rn); o.y = f2bf(x.y * rn);
    o.z = f2bf(x.z * rn); o.w = f2bf(x.w * rn);
    nvn[r2 * D4 + lane] = o;
  }
}

// Fused GEMM (pk_norm [N,256]bf16 x nv_norm [M,256]bf16^T) + exp(sim/2) + row-sum.
// Block: 256 thr = 4 waves (2x2 of 64x64). Tile 128 rows x 128 cols, BK=64, K=256.
// Each WG owns 128 rows x 512 cols (4 col tiles); grid (M/512, N/128).
// LDS XOR-swizzle: chunk' = chunk ^ (row&7)  -> 2-way max on ds_read_b128 (free).
__global__ __launch_bounds__(256) void gemm_lse_kernel(
    const short8* __restrict__ gA, const short8* __restrict__ gB,
    float* __restrict__ rowsum) {
  __shared__ short8 As[128 * 8];
  __shared__ short8 Bs[128 * 8];
  const int tid    = threadIdx.x;
  const int lane   = tid & 63;
  const int wave   = tid >> 6;
  const int wm     = wave >> 1;      // wave row-half (0/1)
  const int wn     = wave & 1;       // wave col-half (0/1)
  const int lane15 = lane & 15;
  const int quad   = lane >> 4;
  const int row0   = blockIdx.y * 128;
  const int cg0    = blockIdx.x * 512;

  const float kLog2eHalf = 0.72134752044448170f;  // log2(e)/2

  float rowpart[4][4];
#pragma unroll
  for (int a = 0; a < 4; a++)
#pragma unroll
    for (int b = 0; b < 4; b++) rowpart[a][b] = 0.f;

  for (int ct = 0; ct < 4; ct++) {
    const int col0 = cg0 + ct * 128;
    f32x4 zero = {0.f, 0.f, 0.f, 0.f};
    f32x4 acc[4][4];
#pragma unroll
    for (int mi = 0; mi < 4; mi++)
#pragma unroll
      for (int ni = 0; ni < 4; ni++) acc[mi][ni] = zero;

#pragma unroll
    for (int kt = 0; kt < 4; kt++) {
      __syncthreads();
#pragma unroll
      for (int i = 0; i < 4; i++) {
        int c  = i * 256 + tid;        // 0..1023 chunk id
        int r  = c >> 3;               // tile row 0..127
        int ch = c & 7;                // 16B chunk within BK=64
        int sw = ch ^ (r & 7);
        As[r * 8 + sw] = gA[(size_t)(row0 + r) * 32 + kt * 8 + ch];
        Bs[r * 8 + sw] = gB[(size_t)(col0 + r) * 32 + kt * 8 + ch];
      }
      __syncthreads();
#pragma unroll
      for (int ks = 0; ks < 2; ks++) {
        short8 af[4], bf[4];
        int chh = ks * 4 + quad;       // k-chunk this lane needs
#pragma unroll
        for (int mi = 0; mi < 4; mi++) {
          int r = wm * 64 + mi * 16 + lane15;
          af[mi] = As[r * 8 + (chh ^ (r & 7))];
        }
#pragma unroll
        for (int ni = 0; ni < 4; ni++) {
          int r = wn * 64 + ni * 16 + lane15;
          bf[ni] = Bs[r * 8 + (chh ^ (r & 7))];
        }
#pragma unroll
        for (int mi = 0; mi < 4; mi++)
#pragma unroll
          for (int ni = 0; ni < 4; ni++)
            acc[mi][ni] = __builtin_amdgcn_mfma_f32_16x16x32_bf16(
                af[mi], bf[ni], acc[mi][ni], 0, 0, 0);
      }
    }
    // Epilogue: exp(sim/2) = exp2(sim * log2e/2); sum over this tile's 64 cols
    // (ni frags now; the 16 lane-cols reduced once at the end).
#pragma unroll
    for (int mi = 0; mi < 4; mi++)
#pragma unroll
      for (int rr = 0; rr < 4; rr++) {
        float s = 0.f;
#pragma unroll
        for (int ni = 0; ni < 4; ni++)
          s += __builtin_amdgcn_exp2f(acc[mi][ni][rr] * kLog2eHalf);
        rowpart[mi][rr] += s;
      }
  }

  // C/D layout: col = lane&15, row = quad*4 + rr. Reduce the 16 lane-columns.
#pragma unroll
  for (int mi = 0; mi < 4; mi++)
#pragma unroll
    for (int rr = 0; rr < 4; rr++) {
      float v = rowpart[mi][rr];
      v += __shfl_xor(v, 1, 16);
      v += __shfl_xor(v, 2, 16);
      v += __shfl_xor(v, 4, 16);
      v += __shfl_xor(v, 8, 16);
      if (lane15 == 0)
        atomicAdd(&rowsum[row0 + wm * 64 + mi * 16 + quad * 4 + rr], v);
    }
}

// mean over rows of ln(rowsum)  (v_log_f32 is log2 -> scale by ln2)
__global__ __launch_bounds__(256) void finalize_kernel(
    const float* __restrict__ rowsum, float* __restrict__ out, int N, float invN) {
  int idx    = blockIdx.x * blockDim.x + threadIdx.x;
  int stride = gridDim.x * blockDim.x;
  float s = 0.f;
  for (int i = idx; i < N; i += stride)
    s += __builtin_amdgcn_logf(rowsum[i]);
#pragma unroll
  for (int m = 32; m >= 1; m >>= 1) s += __shfl_xor(s, m, 64);
  if ((threadIdx.x & 63) == 0)
    atomicAdd(out, s * 0.69314718055994531f * invN);
}

extern "C" void kernel_launch(void* const* d_in, const int* in_sizes, int n_in,
                              void* d_out, int out_size, void* d_ws, size_t ws_size,
                              hipStream_t stream) {
  const float* pk = (const float*)d_in[0];
  const float* pv = (const float*)d_in[1];
  const float* nv = (const float*)d_in[2];
  int N = in_sizes[0] / DIM;   // 8192
  int M = in_sizes[2] / DIM;   // 8192
  float* out = (float*)d_out;

  unsigned short* pkn = (unsigned short*)d_ws;                 // [N,256] bf16
  unsigned short* nvn = pkn + (size_t)N * DIM;                 // [M,256] bf16
  float* rowsum = (float*)(nvn + (size_t)M * DIM);             // [N] fp32

  hipMemsetAsync(out, 0, sizeof(float), stream);
  hipMemsetAsync(rowsum, 0, (size_t)N * sizeof(float), stream);

  normalize_kernel<<<(N + M) / 4, 256, 0, stream>>>(
      (const float4*)pk, (const float4*)pv, (const float4*)nv,
      (ushort4*)pkn, (ushort4*)nvn, out, N, 0.5f / (float)N);

  gemm_lse_kernel<<<dim3(M / 512, N / 128), 256, 0, stream>>>(
      (const short8*)pkn, (const short8*)nvn, rowsum);

  finalize_kernel<<<8, 256, 0, stream>>>(rowsum, out, N, 1.0f / (float)N);
}

// Round 2
// 147.755 us; speedup vs baseline: 1.6918x; 1.6918x over previous
//
#include <hip/hip_runtime.h>

typedef __attribute__((ext_vector_type(8))) short short8;   // 8 bf16 = 4 VGPRs (MFMA A/B frag)
typedef __attribute__((ext_vector_type(4))) float f32x4;    // MFMA C/D frag

#define DIM 256
#define D4  64    // float4 per row

// async global->LDS, 16B per lane. LDS dest is wave-uniform base + lane*16,
// so the bank-conflict swizzle is applied to the GLOBAL source address instead.
#define GLD_LDS16(g, l) __builtin_amdgcn_global_load_lds(                      \
    (const __attribute__((address_space(1))) void*)(g),                        \
    (__attribute__((address_space(3))) void*)(l), 16, 0, 0)

// round-to-nearest-even fp32 -> bf16 (values are finite)
__device__ __forceinline__ unsigned short f2bf(float f) {
  unsigned int u = __float_as_uint(f);
  u += 0x7fffu + ((u >> 16) & 1u);
  return (unsigned short)(u >> 16);
}

// One wave per row. Rows [0,N): pos pair -> pos_sim (exact fp32) written to
// posPart[row] (NO single-address atomic — that serialized 8192 waves at one
// L2 line and cost 110us in R1) + normalized pk (bf16).
// Rows [N,N+M): neg rows -> normalized nv (bf16).
__global__ __launch_bounds__(256) void normalize_kernel(
    const float4* __restrict__ pk, const float4* __restrict__ pv,
    const float4* __restrict__ nv, ushort4* __restrict__ pkn,
    ushort4* __restrict__ nvn, float* __restrict__ posPart, int N) {
  int row  = blockIdx.x * 4 + (threadIdx.x >> 6);
  int lane = threadIdx.x & 63;
  if (row < N) {
    float4 x = pk[row * D4 + lane];
    float4 y = pv[row * D4 + lane];
    float skk = x.x*x.x + x.y*x.y + x.z*x.z + x.w*x.w;
    float svv = y.x*y.x + y.y*y.y + y.z*y.z + y.w*y.w;
    float skv = x.x*y.x + x.y*y.y + x.z*y.z + x.w*y.w;
#pragma unroll
    for (int m = 32; m >= 1; m >>= 1) {
      skk += __shfl_xor(skk, m, 64);
      svv += __shfl_xor(svv, m, 64);
      skv += __shfl_xor(skv, m, 64);
    }
    float nk  = fmaxf(sqrtf(skk), 1e-8f);
    float nvv = fmaxf(sqrtf(svv), 1e-8f);
    if (lane == 0) posPart[row] = skv / (nk * nvv);
    float rk = 1.0f / nk;
    ushort4 o;
    o.x = f2bf(x.x * rk); o.y = f2bf(x.y * rk);
    o.z = f2bf(x.z * rk); o.w = f2bf(x.w * rk);
    pkn[row * D4 + lane] = o;
  } else {
    int r2 = row - N;
    float4 x = nv[r2 * D4 + lane];
    float s = x.x*x.x + x.y*x.y + x.z*x.z + x.w*x.w;
#pragma unroll
    for (int m = 32; m >= 1; m >>= 1) s += __shfl_xor(s, m, 64);
    float rn = 1.0f / fmaxf(sqrtf(s), 1e-8f);
    ushort4 o;
    o.x = f2bf(x.x * rn); o.y = f2bf(x.y * rn);
    o.z = f2bf(x.z * rn); o.w = f2bf(x.w * rn);
    nvn[r2 * D4 + lane] = o;
  }
}

// Fused GEMM (pk_norm [N,256]bf16 x nv_norm [M,256]bf16^T) + exp(sim/2) + row-sum.
// Block: 256 thr = 4 waves (2x2 of 64x64). Tile 128 rows x 128 cols, BK=64, K=256.
// Each WG owns 128 rows x 512 cols (4 col tiles); grid (M/512, N/128).
// Staging: global_load_lds dwordx4; swizzle chunk' = ch ^ (row&7) applied on the
// global-source side (lanes of a row permute within one 128B segment -> still
// coalesced). ds_read_b128 then hits <=2-way bank aliasing (free per m136).
__global__ __launch_bounds__(256) void gemm_lse_kernel(
    const short8* __restrict__ gA, const short8* __restrict__ gB,
    float* __restrict__ rowsum) {
  __shared__ short8 As[128 * 8];
  __shared__ short8 Bs[128 * 8];
  const int tid    = threadIdx.x;
  const int lane   = tid & 63;
  const int wm     = (tid >> 6) >> 1;   // wave row-half (0/1)
  const int wn     = (tid >> 6) & 1;    // wave col-half (0/1)
  const int lane15 = lane & 15;
  const int quad   = lane >> 4;
  const int row0   = blockIdx.y * 128;
  const int cg0    = blockIdx.x * 512;

  const float kLog2eHalf = 0.72134752044448170f;  // log2(e)/2

  float rowpart[4][4];
#pragma unroll
  for (int a = 0; a < 4; a++)
#pragma unroll
    for (int b = 0; b < 4; b++) rowpart[a][b] = 0.f;

  for (int ct = 0; ct < 4; ct++) {
    const int col0 = cg0 + ct * 128;
    f32x4 zero = {0.f, 0.f, 0.f, 0.f};
    f32x4 acc[4][4];
#pragma unroll
    for (int mi = 0; mi < 4; mi++)
#pragma unroll
      for (int ni = 0; ni < 4; ni++) acc[mi][ni] = zero;

#pragma unroll
    for (int kt = 0; kt < 4; kt++) {
      __syncthreads();
#pragma unroll
      for (int i = 0; i < 4; i++) {
        int slot = i * 256 + tid;      // linear LDS slot; lane-contiguous per wave
        int r    = slot >> 3;          // tile row 0..127
        int ch   = (slot & 7) ^ (r & 7);  // source-side swizzle
        GLD_LDS16(&gA[(size_t)(row0 + r) * 32 + kt * 8 + ch], &As[slot]);
        GLD_LDS16(&gB[(size_t)(col0 + r) * 32 + kt * 8 + ch], &Bs[slot]);
      }
      __syncthreads();
#pragma unroll
      for (int ks = 0; ks < 2; ks++) {
        short8 af[4], bf[4];
        int chh = ks * 4 + quad;       // k-chunk this lane needs
#pragma unroll
        for (int mi = 0; mi < 4; mi++) {
          int r = wm * 64 + mi * 16 + lane15;
          af[mi] = As[r * 8 + (chh ^ (r & 7))];
        }
#pragma unroll
        for (int ni = 0; ni < 4; ni++) {
          int r = wn * 64 + ni * 16 + lane15;
          bf[ni] = Bs[r * 8 + (chh ^ (r & 7))];
        }
#pragma unroll
        for (int mi = 0; mi < 4; mi++)
#pragma unroll
          for (int ni = 0; ni < 4; ni++)
            acc[mi][ni] = __builtin_amdgcn_mfma_f32_16x16x32_bf16(
                af[mi], bf[ni], acc[mi][ni], 0, 0, 0);
      }
    }
    // Epilogue: exp(sim/2) = exp2(sim * log2e/2); accumulate this tile's 64 cols.
#pragma unroll
    for (int mi = 0; mi < 4; mi++)
#pragma unroll
      for (int rr = 0; rr < 4; rr++) {
        float s = 0.f;
#pragma unroll
        for (int ni = 0; ni < 4; ni++)
          s += __builtin_amdgcn_exp2f(acc[mi][ni][rr] * kLog2eHalf);
        rowpart[mi][rr] += s;
      }
  }

  // C/D layout: col = lane&15, row = quad*4 + rr. Reduce the 16 lane-columns.
#pragma unroll
  for (int mi = 0; mi < 4; mi++)
#pragma unroll
    for (int rr = 0; rr < 4; rr++) {
      float v = rowpart[mi][rr];
      v += __shfl_xor(v, 1, 16);
      v += __shfl_xor(v, 2, 16);
      v += __shfl_xor(v, 4, 16);
      v += __shfl_xor(v, 8, 16);
      if (lane15 == 0)
        atomicAdd(&rowsum[row0 + wm * 64 + mi * 16 + quad * 4 + rr], v);
    }
}

// out = mean(ln(rowsum)) - 0.5*mean(posPart); v_log_f32 is log2 -> scale by ln2.
__global__ __launch_bounds__(256) void finalize_kernel(
    const float* __restrict__ rowsum, const float* __restrict__ posPart,
    float* __restrict__ out, int N, float invN) {
  int idx    = blockIdx.x * blockDim.x + threadIdx.x;
  int stride = gridDim.x * blockDim.x;
  float slog = 0.f, spos = 0.f;
  for (int i = idx; i < N; i += stride) {
    slog += __builtin_amdgcn_logf(rowsum[i]);
    spos += posPart[i];
  }
#pragma unroll
  for (int m = 32; m >= 1; m >>= 1) {
    slog += __shfl_xor(slog, m, 64);
    spos += __shfl_xor(spos, m, 64);
  }
  if ((threadIdx.x & 63) == 0)
    atomicAdd(out, (slog * 0.69314718055994531f - 0.5f * spos) * invN);
}

extern "C" void kernel_launch(void* const* d_in, const int* in_sizes, int n_in,
                              void* d_out, int out_size, void* d_ws, size_t ws_size,
                              hipStream_t stream) {
  const float* pk = (const float*)d_in[0];
  const float* pv = (const float*)d_in[1];
  const float* nv = (const float*)d_in[2];
  int N = in_sizes[0] / DIM;   // 8192
  int M = in_sizes[2] / DIM;   // 8192
  float* out = (float*)d_out;

  unsigned short* pkn = (unsigned short*)d_ws;                 // [N,256] bf16
  unsigned short* nvn = pkn + (size_t)N * DIM;                 // [M,256] bf16
  float* rowsum  = (float*)(nvn + (size_t)M * DIM);            // [N] fp32
  float* posPart = rowsum + N;                                 // [N] fp32

  hipMemsetAsync(out, 0, sizeof(float), stream);
  hipMemsetAsync(rowsum, 0, (size_t)N * sizeof(float), stream);

  normalize_kernel<<<(N + M) / 4, 256, 0, stream>>>(
      (const float4*)pk, (const float4*)pv, (const float4*)nv,
      (ushort4*)pkn, (ushort4*)nvn, posPart, N);

  gemm_lse_kernel<<<dim3(M / 512, N / 128), 256, 0, stream>>>(
      (const short8*)pkn, (const short8*)nvn, rowsum);

  finalize_kernel<<<8, 256, 0, stream>>>(rowsum, posPart, out, N, 1.0f / (float)N);
}

// Round 3
// 127.625 us; speedup vs baseline: 1.9586x; 1.1577x over previous
//
#include <hip/hip_runtime.h>

typedef __attribute__((ext_vector_type(4))) float f32x4;
typedef __attribute__((ext_vector_type(2))) long vlong2;   // 16B: two fp8 MFMA frags

#define DIM 256
#define D4  64    // float4 per row

// async global->LDS, 16B per lane; LDS dest = wave-uniform base + lane*16.
#define GLD_LDS16(g, l) __builtin_amdgcn_global_load_lds(                      \
    (const __attribute__((address_space(1))) void*)(g),                        \
    (__attribute__((address_space(3))) void*)(l), 16, 0, 0)

// ---------------------------------------------------------------------------
// Global fp8 layout (per 256-elt row, 256 bytes), designed for MFMA frags:
//   element k -> byte pos = q*64 + s*8 + j   where s=k>>5 (K-step of 32),
//   q=(k>>3)&3 (lane quad), j=k&7.  A lane's frags for steps 2s2,2s2+1 are the
//   16B at q*64 + s2*16.  Staging additionally XORs the 16B-chunk index with
//   (row&15) so ds_read_b128 frag fetches spread evenly over LDS bank quads.
// ---------------------------------------------------------------------------

// One wave per row. Rows [0,N): pos pair -> exact fp32 pos_sim into posPart[row]
// + normalized pk quantized to fp8 e4m3. Rows [N,N+M): normalized nv -> fp8.
__global__ __launch_bounds__(256) void normalize_kernel(
    const float4* __restrict__ pk, const float4* __restrict__ pv,
    const float4* __restrict__ nv, unsigned int* __restrict__ pkn,
    unsigned int* __restrict__ nvn, float* __restrict__ posPart, int N) {
  int row  = blockIdx.x * 4 + (threadIdx.x >> 6);
  int lane = threadIdx.x & 63;
  // dword slot within the 64-dword swizzled row for this lane's k=4*lane..+3:
  int dw = ((lane >> 1) & 3) * 16 + (lane >> 3) * 2 + (lane & 1);
  if (row < N) {
    float4 x = pk[row * D4 + lane];
    float4 y = pv[row * D4 + lane];
    float skk = x.x*x.x + x.y*x.y + x.z*x.z + x.w*x.w;
    float svv = y.x*y.x + y.y*y.y + y.z*y.z + y.w*y.w;
    float skv = x.x*y.x + x.y*y.y + x.z*y.z + x.w*y.w;
#pragma unroll
    for (int m = 32; m >= 1; m >>= 1) {
      skk += __shfl_xor(skk, m, 64);
      svv += __shfl_xor(svv, m, 64);
      skv += __shfl_xor(skv, m, 64);
    }
    float nk  = fmaxf(sqrtf(skk), 1e-8f);
    float nvv = fmaxf(sqrtf(svv), 1e-8f);
    if (lane == 0) posPart[row] = skv / (nk * nvv);
    float rk = 1.0f / nk;
    int w = __builtin_amdgcn_cvt_pk_fp8_f32(x.x * rk, x.y * rk, 0, false);
    w = __builtin_amdgcn_cvt_pk_fp8_f32(x.z * rk, x.w * rk, w, true);
    pkn[(size_t)row * 64 + dw] = (unsigned int)w;
  } else {
    int r2 = row - N;
    float4 x = nv[r2 * D4 + lane];
    float s = x.x*x.x + x.y*x.y + x.z*x.z + x.w*x.w;
#pragma unroll
    for (int m = 32; m >= 1; m >>= 1) s += __shfl_xor(s, m, 64);
    float rn = 1.0f / fmaxf(sqrtf(s), 1e-8f);
    int w = __builtin_amdgcn_cvt_pk_fp8_f32(x.x * rn, x.y * rn, 0, false);
    w = __builtin_amdgcn_cvt_pk_fp8_f32(x.z * rn, x.w * rn, w, true);
    nvn[(size_t)r2 * 64 + dw] = (unsigned int)w;
  }
}

// Fused fp8 GEMM + exp(sim/2) + row-sum.  WG 256 thr = 4 waves (2x2 of 64x64
// wave tiles, each 4x4 of mfma_f32_16x16x32_fp8_fp8).  WG tile 128x128, full
// K=256 staged once (A 32KB + B 32KB) -> ONE barrier drain per WG (the R2
// version had 32; its serialized stage->read->MFMA chain was the 75us).
// Grid 64x64 = 4096 WGs = 16/CU of work, 2 resident (64KB LDS).
__global__ __launch_bounds__(256, 2) void gemm_lse_kernel(
    const unsigned char* __restrict__ gA, const unsigned char* __restrict__ gB,
    float* __restrict__ rowsum) {
  __shared__ unsigned char smem[65536];
  unsigned char* As = smem;            // [128 rows][256B swizzled]
  unsigned char* Bs = smem + 32768;
  float* epi = (float*)smem;           // reused: [32 slots][128 rows] + swizzle

  const int tid  = threadIdx.x;
  const int lane = tid & 63;
  const int wv   = tid >> 6;
  const int wm   = wv >> 1, wn = wv & 1;
  const int l15  = lane & 15, q = lane >> 4;
  const int row0 = blockIdx.y * 128;
  const int col0 = blockIdx.x * 128;
  const float kLog2eHalf = 0.72134752044448170f;  // log2(e)/2

  // ---- stage A and B: 4096 chunks of 16B, 16 per thread, one drain ----
#pragma unroll
  for (int i = 0; i < 8; i++) {
    int c   = i * 256 + tid;           // chunk 0..2047
    int r   = c >> 4;
    int src = ((c & 15) ^ (r & 15)) << 4;
    GLD_LDS16(gA + (size_t)(row0 + r) * 256 + src, As + c * 16);
  }
#pragma unroll
  for (int i = 0; i < 8; i++) {
    int c   = i * 256 + tid;
    int r   = c >> 4;
    int src = ((c & 15) ^ (r & 15)) << 4;
    GLD_LDS16(gB + (size_t)(col0 + r) * 256 + src, Bs + c * 16);
  }
  __syncthreads();

  f32x4 acc[4][4];
#pragma unroll
  for (int mi = 0; mi < 4; mi++)
#pragma unroll
    for (int ni = 0; ni < 4; ni++) acc[mi][ni] = (f32x4){0.f, 0.f, 0.f, 0.f};

  // ---- K loop: 4 x (2 K-steps), 128 MFMA, zero barriers ----
#pragma unroll
  for (int s2 = 0; s2 < 4; s2++) {
    vlong2 af[4], bf[4];
#pragma unroll
    for (int mi = 0; mi < 4; mi++) {
      int r   = wm * 64 + mi * 16 + l15;
      int c16 = (q * 4 + s2) ^ (r & 15);
      af[mi] = *(const vlong2*)(As + r * 256 + c16 * 16);
    }
#pragma unroll
    for (int ni = 0; ni < 4; ni++) {
      int r   = wn * 64 + ni * 16 + l15;
      int c16 = (q * 4 + s2) ^ (r & 15);
      bf[ni] = *(const vlong2*)(Bs + r * 256 + c16 * 16);
    }
#pragma unroll
    for (int mi = 0; mi < 4; mi++)
#pragma unroll
      for (int ni = 0; ni < 4; ni++)
        acc[mi][ni] = __builtin_amdgcn_mfma_f32_16x16x32_fp8_fp8(
            af[mi].x, bf[ni].x, acc[mi][ni], 0, 0, 0);
#pragma unroll
    for (int mi = 0; mi < 4; mi++)
#pragma unroll
      for (int ni = 0; ni < 4; ni++)
        acc[mi][ni] = __builtin_amdgcn_mfma_f32_16x16x32_fp8_fp8(
            af[mi].y, bf[ni].y, acc[mi][ni], 0, 0, 0);
  }

  // ---- epilogue: exp2(sim*log2e/2), partial row-sums over ni tiles ----
  // C/D layout (m89-verified): col=lane&15, row=quad*4+reg.
  f32x4 rp[4];
#pragma unroll
  for (int mi = 0; mi < 4; mi++)
#pragma unroll
    for (int rr = 0; rr < 4; rr++) {
      float s = 0.f;
#pragma unroll
      for (int ni = 0; ni < 4; ni++)
        s += __builtin_amdgcn_exp2f(acc[mi][ni][rr] * kLog2eHalf);
      rp[mi][rr] = s;
    }

  __syncthreads();                       // done with As/Bs; reuse as epi scratch
  int slot = wn * 16 + l15;              // 0..31 (col-lane id)
#pragma unroll
  for (int mi = 0; mi < 4; mi++) {
    int row = wm * 64 + mi * 16 + q * 4; // 4-aligned row base of this f32x4
    int rb  = (row >> 2) ^ (slot & 7);   // bank swizzle on 4-row blocks
    *(f32x4*)(epi + slot * 128 + rb * 4) = rp[mi];
  }
  __syncthreads();

  if (tid < 128) {
    int rg = tid >> 2;                   // rows rg*4..+3
    int cq = tid & 3;                    // slots cq*8..+8
    f32x4 s = {0.f, 0.f, 0.f, 0.f};
#pragma unroll
    for (int i = 0; i < 8; i++) {
      int sl = cq * 8 + i;
      int rb = rg ^ (sl & 7);
      s += *(const f32x4*)(epi + sl * 128 + rb * 4);
    }
    s.x += __shfl_down(s.x, 1); s.y += __shfl_down(s.y, 1);
    s.z += __shfl_down(s.z, 1); s.w += __shfl_down(s.w, 1);
    s.x += __shfl_down(s.x, 2); s.y += __shfl_down(s.y, 2);
    s.z += __shfl_down(s.z, 2); s.w += __shfl_down(s.w, 2);
    if (cq == 0) {
      int row = row0 + rg * 4;
      atomicAdd(&rowsum[row + 0], s.x);
      atomicAdd(&rowsum[row + 1], s.y);
      atomicAdd(&rowsum[row + 2], s.z);
      atomicAdd(&rowsum[row + 3], s.w);
    }
  }
}

// out = mean(ln(rowsum)) - 0.5*mean(posPart); v_log_f32 is log2 -> scale by ln2.
__global__ __launch_bounds__(256) void finalize_kernel(
    const float* __restrict__ rowsum, const float* __restrict__ posPart,
    float* __restrict__ out, int N, float invN) {
  int idx    = blockIdx.x * blockDim.x + threadIdx.x;
  int stride = gridDim.x * blockDim.x;
  float slog = 0.f, spos = 0.f;
  for (int i = idx; i < N; i += stride) {
    slog += __builtin_amdgcn_logf(rowsum[i]);
    spos += posPart[i];
  }
#pragma unroll
  for (int m = 32; m >= 1; m >>= 1) {
    slog += __shfl_xor(slog, m, 64);
    spos += __shfl_xor(spos, m, 64);
  }
  if ((threadIdx.x & 63) == 0)
    atomicAdd(out, (slog * 0.69314718055994531f - 0.5f * spos) * invN);
}

extern "C" void kernel_launch(void* const* d_in, const int* in_sizes, int n_in,
                              void* d_out, int out_size, void* d_ws, size_t ws_size,
                              hipStream_t stream) {
  const float* pk = (const float*)d_in[0];
  const float* pv = (const float*)d_in[1];
  const float* nv = (const float*)d_in[2];
  int N = in_sizes[0] / DIM;   // 8192
  int M = in_sizes[2] / DIM;   // 8192
  float* out = (float*)d_out;

  unsigned char* pkn = (unsigned char*)d_ws;                   // [N,256] fp8 (swizzled)
  unsigned char* nvn = pkn + (size_t)N * DIM;                  // [M,256] fp8 (swizzled)
  float* rowsum  = (float*)(nvn + (size_t)M * DIM);            // [N] fp32
  float* posPart = rowsum + N;                                 // [N] fp32

  hipMemsetAsync(out, 0, sizeof(float), stream);
  hipMemsetAsync(rowsum, 0, (size_t)N * sizeof(float), stream);

  normalize_kernel<<<(N + M) / 4, 256, 0, stream>>>(
      (const float4*)pk, (const float4*)pv, (const float4*)nv,
      (unsigned int*)pkn, (unsigned int*)nvn, posPart, N);

  gemm_lse_kernel<<<dim3(M / 128, N / 128), 256, 0, stream>>>(
      pkn, nvn, rowsum);

  finalize_kernel<<<8, 256, 0, stream>>>(rowsum, posPart, out, N, 1.0f / (float)N);
}